// Round 2
// baseline (393.660 us; speedup 1.0000x reference)
//
#include <hip/hip_runtime.h>
#include <hip/hip_bf16.h>
#include <stdint.h>

// Problem: B=2, S=2048, D=1024, H=16, DK=64.  M = B*S = 4096.
// Dtype is detected at runtime (fp32 vs bf16) and canonicalized to bf16.

typedef __attribute__((ext_vector_type(4))) float f32x4;
typedef __attribute__((ext_vector_type(4))) int   i32x4;
typedef __attribute__((ext_vector_type(8))) __bf16 bf16x8;

#define MFMA16(a, b, c) __builtin_amdgcn_mfma_f32_16x16x32_bf16((a), (b), (c), 0, 0, 0)

__device__ __forceinline__ void async16(const void* g, void* lds) {
  __builtin_amdgcn_global_load_lds(
      (const __attribute__((address_space(1))) uint32_t*)g,
      (__attribute__((address_space(3))) uint32_t*)lds,
      16, 0, 0);
}

// ---- dtype detector: read w_q as bf16; fp32 mantissa low-halves decode huge.
__global__ void detect_dtype(const uint16_t* __restrict__ w, int* __restrict__ flag) {
  __shared__ int s;
  if (threadIdx.x == 0) s = 0;
  __syncthreads();
  int big = 0;
  for (int i = threadIdx.x; i < 8192; i += 256) {
    uint32_t u = ((uint32_t)w[i]) << 16;
    float f;
    __builtin_memcpy(&f, &u, 4);
    if (fabsf(f) > 1.0f) big = 1;   // xavier bound is 0.054; fp32 garbage exceeds 1
  }
  if (big) atomicOr(&s, 1);
  __syncthreads();
  if (threadIdx.x == 0) *flag = s;  // 1 = fp32 inputs, 0 = bf16 inputs
}

// ---- canonicalize all float tensors to bf16
struct CvtArgs { const void* src[8]; void* dst[8]; int n[8]; };

__global__ __launch_bounds__(256)
void convert_all(CvtArgs a, const int* __restrict__ flagp) {
  const int t = blockIdx.y;
  const int n = a.n[t];
  const int i0 = (blockIdx.x * 256 + threadIdx.x) * 8;
  if (i0 >= n) return;
  const int f = *flagp;
  if (f) {                                    // fp32 -> bf16
    const float* s = (const float*)a.src[t];
    __bf16* d = (__bf16*)a.dst[t];
    bf16x8 v;
#pragma unroll
    for (int j = 0; j < 8; ++j) v[j] = (__bf16)s[i0 + j];
    *(bf16x8*)(d + i0) = v;
  } else {                                    // bf16 bit-copy (16B)
    const i32x4* s = (const i32x4*)((const char*)a.src[t] + (size_t)i0 * 2);
    i32x4* d = (i32x4*)((char*)a.dst[t] + (size_t)i0 * 2);
    *d = *s;
  }
}

// C = A[4096,1024] @ W[1024,1024]^T  (NT gemm, both K-contiguous, bf16)
// mode 0: store to [B*H][S][64] bf16 (QKV layout), bias ignored, scale applied
// mode 1: store to [4096][1024] with bias; fp32 or bf16 store per *flagp
__global__ __launch_bounds__(256, 2)
void gemm_nt(const __bf16* __restrict__ A,
             const __bf16* __restrict__ W,
             void* __restrict__ C,
             const __bf16* __restrict__ bias,
             float scale, int mode, const int* __restrict__ flagp)
{
  constexpr int K = 1024;
  __shared__ __align__(16) __bf16 As[128 * 32];
  __shared__ __align__(16) __bf16 Bs[64 * 32];

  const int tid = threadIdx.x;
  const int lane = tid & 63;
  const int wave = tid >> 6;
  const int l15 = lane & 15;
  const int quad = lane >> 4;
  const int bm = blockIdx.y * 128;
  const int bn = blockIdx.x * 64;
  const int wm = (wave >> 1) * 64;   // wave covers 64x32 of the 128x64 tile
  const int wn = (wave & 1) * 32;

  const int srow = lane >> 2;        // row within a 16-row staging segment
  const int scol = (lane & 3) * 8;   // bf16 col offset within BK=32

  f32x4 acc[4][2];
#pragma unroll
  for (int mi = 0; mi < 4; ++mi)
#pragma unroll
    for (int ni = 0; ni < 2; ++ni) {
      f32x4 z = {0.f, 0.f, 0.f, 0.f};
      acc[mi][ni] = z;
    }

  for (int kt = 0; kt < K / 32; ++kt) {
    const int k0 = kt * 32;
    __syncthreads();
#pragma unroll
    for (int c = 0; c < 2; ++c) {
      const int seg = wave + c * 4;
      async16(A + (size_t)(bm + seg * 16 + srow) * K + k0 + scol, As + seg * 512);
    }
    async16(W + (size_t)(bn + wave * 16 + srow) * K + k0 + scol, Bs + wave * 512);
    __syncthreads();

    bf16x8 af[4];
    bf16x8 bfr[2];
#pragma unroll
    for (int mi = 0; mi < 4; ++mi)
      af[mi] = *(const bf16x8*)(As + (wm + mi * 16 + l15) * 32 + quad * 8);
#pragma unroll
    for (int ni = 0; ni < 2; ++ni)
      bfr[ni] = *(const bf16x8*)(Bs + (wn + ni * 16 + l15) * 32 + quad * 8);
#pragma unroll
    for (int mi = 0; mi < 4; ++mi)
#pragma unroll
      for (int ni = 0; ni < 2; ++ni)
        acc[mi][ni] = MFMA16(af[mi], bfr[ni], acc[mi][ni]);
  }

  // Epilogue.  C/D layout: col = lane&15, row = quad*4 + r  [m89-verified]
  const int f = (mode == 1) ? *flagp : 0;
#pragma unroll
  for (int ni = 0; ni < 2; ++ni) {
    const int n = bn + wn + ni * 16 + l15;
    const float bv = (mode == 1) ? (float)bias[n] : 0.0f;
#pragma unroll
    for (int mi = 0; mi < 4; ++mi) {
#pragma unroll
      for (int r = 0; r < 4; ++r) {
        const int m = bm + wm + mi * 16 + quad * 4 + r;
        const float v = acc[mi][ni][r] * scale + bv;
        if (mode == 0) {
          const int b = m >> 11, s = m & 2047, h = n >> 6, dk = n & 63;
          ((__bf16*)C)[((size_t)(b * 16 + h) * 2048 + s) * 64 + dk] = (__bf16)v;
        } else if (f) {
          ((float*)C)[(size_t)m * 1024 + n] = v;
        } else {
          ((__bf16*)C)[(size_t)m * 1024 + n] = (__bf16)v;
        }
      }
    }
  }
}

// Flash attention: one block = 64 q rows of one (b,h).  Q pre-scaled by 1/8.
// Q/K/V layout [B*H][2048][64] bf16.  Output [b*2048+q][h*64+d] bf16.
__global__ __launch_bounds__(256, 2)
void attn(const __bf16* __restrict__ Q,
          const __bf16* __restrict__ Kg,
          const __bf16* __restrict__ Vg,
          __bf16* __restrict__ O)
{
  __shared__ __align__(16) __bf16 Qs[64][72];
  __shared__ __align__(16) __bf16 Ks[64][72];
  __shared__ __align__(16) __bf16 Vts[64][72];   // Vts[d][k]
  __shared__ __align__(16) __bf16 Ps[4][16][72]; // per-wave P strips

  const int tid = threadIdx.x;
  const int lane = tid & 63;
  const int wave = tid >> 6;
  const int l15 = lane & 15;
  const int quad = lane >> 4;
  const int qt = blockIdx.x;   // 0..31
  const int bh = blockIdx.y;   // 0..31
  const int q0 = qt * 64;

  const __bf16* Qp = Q + (size_t)bh * 2048 * 64;
  const __bf16* Kp = Kg + (size_t)bh * 2048 * 64;
  const __bf16* Vp = Vg + (size_t)bh * 2048 * 64;

  for (int i = tid; i < 512; i += 256) {
    const int row = i >> 3, c = i & 7;
    *(f32x4*)(&Qs[row][c * 8]) = *(const f32x4*)(Qp + (size_t)(q0 + row) * 64 + c * 8);
  }

  f32x4 o_[4];
  f32x4 mrow, lrow;
#pragma unroll
  for (int nt = 0; nt < 4; ++nt) {
    f32x4 z = {0.f, 0.f, 0.f, 0.f};
    o_[nt] = z;
  }
#pragma unroll
  for (int r = 0; r < 4; ++r) { mrow[r] = -1e30f; lrow[r] = 0.0f; }

  for (int kt = 0; kt <= qt; ++kt) {
    const int k0 = kt * 64;
    __syncthreads();
    for (int i = tid; i < 512; i += 256) {
      const int row = i >> 3, c = i & 7;
      *(f32x4*)(&Ks[row][c * 8]) = *(const f32x4*)(Kp + (size_t)(k0 + row) * 64 + c * 8);
    }
    for (int i = tid; i < 512; i += 256) {
      const int k = i >> 3, c = i & 7;
      f32x4 v = *(const f32x4*)(Vp + (size_t)(k0 + k) * 64 + c * 8);
      const __bf16* pv = (const __bf16*)&v;
#pragma unroll
      for (int j = 0; j < 8; ++j) Vts[c * 8 + j][k] = pv[j];
    }
    __syncthreads();

    f32x4 sc[4];
#pragma unroll
    for (int nt = 0; nt < 4; ++nt) {
      f32x4 z = {0.f, 0.f, 0.f, 0.f};
      sc[nt] = z;
    }
#pragma unroll
    for (int kc = 0; kc < 2; ++kc) {
      bf16x8 aq = *(const bf16x8*)(&Qs[wave * 16 + l15][kc * 32 + quad * 8]);
#pragma unroll
      for (int nt = 0; nt < 4; ++nt) {
        bf16x8 bk = *(const bf16x8*)(&Ks[nt * 16 + l15][kc * 32 + quad * 8]);
        sc[nt] = MFMA16(aq, bk, sc[nt]);
      }
    }

    if (kt == qt) {  // diagonal tile: mask col > row
#pragma unroll
      for (int nt = 0; nt < 4; ++nt) {
        const int col = nt * 16 + l15;
#pragma unroll
        for (int r = 0; r < 4; ++r) {
          const int rowl = wave * 16 + quad * 4 + r;
          if (col > rowl) sc[nt][r] = -1e30f;
        }
      }
    }

    f32x4 rmax;
#pragma unroll
    for (int r = 0; r < 4; ++r)
      rmax[r] = fmaxf(fmaxf(sc[0][r], sc[1][r]), fmaxf(sc[2][r], sc[3][r]));
#pragma unroll
    for (int off = 1; off < 16; off <<= 1)
#pragma unroll
      for (int r = 0; r < 4; ++r)
        rmax[r] = fmaxf(rmax[r], __shfl_xor(rmax[r], off, 64));

    f32x4 mnew, alpha;
#pragma unroll
    for (int r = 0; r < 4; ++r) {
      mnew[r] = fmaxf(mrow[r], rmax[r]);
      alpha[r] = __expf(mrow[r] - mnew[r]);
    }
    f32x4 p[4];
#pragma unroll
    for (int nt = 0; nt < 4; ++nt)
#pragma unroll
      for (int r = 0; r < 4; ++r)
        p[nt][r] = __expf(sc[nt][r] - mnew[r]);
    f32x4 rs;
#pragma unroll
    for (int r = 0; r < 4; ++r)
      rs[r] = p[0][r] + p[1][r] + p[2][r] + p[3][r];
#pragma unroll
    for (int off = 1; off < 16; off <<= 1)
#pragma unroll
      for (int r = 0; r < 4; ++r)
        rs[r] += __shfl_xor(rs[r], off, 64);
#pragma unroll
    for (int r = 0; r < 4; ++r) {
      lrow[r] = lrow[r] * alpha[r] + rs[r];
      mrow[r] = mnew[r];
    }
#pragma unroll
    for (int nt = 0; nt < 4; ++nt)
#pragma unroll
      for (int r = 0; r < 4; ++r)
        o_[nt][r] *= alpha[r];

#pragma unroll
    for (int nt = 0; nt < 4; ++nt)
#pragma unroll
      for (int r = 0; r < 4; ++r)
        Ps[wave][quad * 4 + r][nt * 16 + l15] = (__bf16)p[nt][r];

    __syncthreads();

#pragma unroll
    for (int kc = 0; kc < 2; ++kc) {
      bf16x8 ap = *(const bf16x8*)(&Ps[wave][l15][kc * 32 + quad * 8]);
#pragma unroll
      for (int nt = 0; nt < 4; ++nt) {
        bf16x8 bv = *(const bf16x8*)(&Vts[nt * 16 + l15][kc * 32 + quad * 8]);
        o_[nt] = MFMA16(ap, bv, o_[nt]);
      }
    }
  }

  const int b = bh >> 4, h = bh & 15;
#pragma unroll
  for (int nt = 0; nt < 4; ++nt) {
#pragma unroll
    for (int r = 0; r < 4; ++r) {
      const int qrow = q0 + wave * 16 + quad * 4 + r;
      const int col = h * 64 + nt * 16 + l15;
      O[(size_t)(b * 2048 + qrow) * 1024 + col] = (__bf16)(o_[nt][r] / lrow[r]);
    }
  }
}

extern "C" void kernel_launch(void* const* d_in, const int* in_sizes, int n_in,
                              void* d_out, int out_size, void* d_ws, size_t ws_size,
                              hipStream_t stream) {
  char* ws = (char*)d_ws;
  int* flag = (int*)ws;
  __bf16* Xc0 = (__bf16*)(ws + (1u << 20));    // 8 MB each
  __bf16* Xc1 = (__bf16*)(ws + (9u << 20));
  __bf16* Xc2 = (__bf16*)(ws + (17u << 20));
  __bf16* Wc0 = (__bf16*)(ws + (25u << 20));   // 2 MB each
  __bf16* Wc1 = (__bf16*)(ws + (27u << 20));
  __bf16* Wc2 = (__bf16*)(ws + (29u << 20));
  __bf16* Wc3 = (__bf16*)(ws + (31u << 20));
  __bf16* bc  = (__bf16*)(ws + (33u << 20));   // 2 KB
  __bf16* Qw  = (__bf16*)(ws + (34u << 20));   // 8 MB each, [B*H][S][64]
  __bf16* Kw  = (__bf16*)(ws + (42u << 20));
  __bf16* Vw  = (__bf16*)(ws + (50u << 20));
  __bf16* Aw  = Xc0;                           // alias: X dead after projections

  detect_dtype<<<1, 256, 0, stream>>>((const uint16_t*)d_in[4], flag);

  CvtArgs ca;
  ca.src[0] = d_in[0]; ca.dst[0] = Xc0; ca.n[0] = 4194304;
  ca.src[1] = d_in[1]; ca.dst[1] = Xc1; ca.n[1] = 4194304;
  ca.src[2] = d_in[2]; ca.dst[2] = Xc2; ca.n[2] = 4194304;
  ca.src[3] = d_in[4]; ca.dst[3] = Wc0; ca.n[3] = 1048576;
  ca.src[4] = d_in[5]; ca.dst[4] = Wc1; ca.n[4] = 1048576;
  ca.src[5] = d_in[6]; ca.dst[5] = Wc2; ca.n[5] = 1048576;
  ca.src[6] = d_in[7]; ca.dst[6] = Wc3; ca.n[6] = 1048576;
  ca.src[7] = d_in[8]; ca.dst[7] = bc;  ca.n[7] = 1024;
  convert_all<<<dim3(2048, 8), 256, 0, stream>>>(ca, flag);

  dim3 gg(16, 32), blk(256);
  // scores = (Q Wq^T)(K Wk^T)^T / 8  -> fold 1/8 into Q projection
  gemm_nt<<<gg, blk, 0, stream>>>(Xc0, Wc0, Qw, nullptr, 0.125f, 0, flag);
  gemm_nt<<<gg, blk, 0, stream>>>(Xc1, Wc1, Kw, nullptr, 1.0f, 0, flag);
  gemm_nt<<<gg, blk, 0, stream>>>(Xc2, Wc2, Vw, nullptr, 1.0f, 0, flag);
  attn<<<dim3(32, 32), blk, 0, stream>>>(Qw, Kw, Vw, Aw);
  gemm_nt<<<gg, blk, 0, stream>>>(Aw, Wc3, d_out, bc, 1.0f, 1, flag);
}

// Round 4
// 259.553 us; speedup vs baseline: 1.5167x; 1.5167x over previous
//
#include <hip/hip_runtime.h>
#include <hip/hip_bf16.h>
#include <stdint.h>

// Problem: B=2, S=2048, D=1024, H=16, DK=64.  M = B*S = 4096.
// Dtype detected at runtime (fp32 vs bf16), canonicalized to bf16.

typedef __attribute__((ext_vector_type(4))) float  f32x4;
typedef __attribute__((ext_vector_type(4))) int    i32x4;
typedef __attribute__((ext_vector_type(8))) __bf16 bf16x8;
typedef __attribute__((ext_vector_type(4))) __bf16 bf16x4;
typedef __attribute__((ext_vector_type(2))) __bf16 bf16x2;

#define MFMA16(a, b, c) __builtin_amdgcn_mfma_f32_16x16x32_bf16((a), (b), (c), 0, 0, 0)

__device__ __forceinline__ void async16(const void* g, void* lds) {
  __builtin_amdgcn_global_load_lds(
      (const __attribute__((address_space(1))) uint32_t*)g,
      (__attribute__((address_space(3))) uint32_t*)lds,
      16, 0, 0);
}

// XOR-swizzled LDS tile: element (row, col) chunk c=col/8 stored at chunk
// row*8 + (c ^ (row&7)).  16B-chunk granularity, unpadded, ~2-way on frag reads.
__device__ __forceinline__ bf16x8 lds_swz_read(const __bf16* base, int row, int cchunk) {
  const int sw = cchunk ^ (row & 7);
  return *(const bf16x8*)((const char*)base + row * 128 + sw * 16);
}

// ---- dtype detector: read w_q as bf16; fp32 mantissa low-halves decode huge.
__global__ void detect_dtype(const uint16_t* __restrict__ w, int* __restrict__ flag) {
  __shared__ int s;
  if (threadIdx.x == 0) s = 0;
  __syncthreads();
  int big = 0;
  for (int i = threadIdx.x; i < 8192; i += 256) {
    uint32_t u = ((uint32_t)w[i]) << 16;
    float f;
    __builtin_memcpy(&f, &u, 4);
    if (fabsf(f) > 1.0f) big = 1;   // xavier bound is 0.054
  }
  if (big) atomicOr(&s, 1);
  __syncthreads();
  if (threadIdx.x == 0) *flag = s;  // 1 = fp32 inputs, 0 = bf16 inputs
}

// ---- canonicalize all float tensors to bf16
struct CvtArgs { const void* src[8]; void* dst[8]; int n[8]; };

__global__ __launch_bounds__(256)
void convert_all(CvtArgs a, const int* __restrict__ flagp) {
  const int t = blockIdx.y;
  const int n = a.n[t];
  const int i0 = (blockIdx.x * 256 + threadIdx.x) * 8;
  if (i0 >= n) return;
  const int f = *flagp;
  if (f) {
    const float* s = (const float*)a.src[t];
    __bf16* d = (__bf16*)a.dst[t];
    bf16x8 v;
#pragma unroll
    for (int j = 0; j < 8; ++j) v[j] = (__bf16)s[i0 + j];
    *(bf16x8*)(d + i0) = v;
  } else {
    const i32x4* s = (const i32x4*)((const char*)a.src[t] + (size_t)i0 * 2);
    i32x4* d = (i32x4*)((char*)a.dst[t] + (size_t)i0 * 2);
    *d = *s;
  }
}

// C = A[4096,1024] @ W[1024,1024]^T  (NT, both K-contiguous, bf16).
// z-batched over up to 3 tensors.  mode 0: QKV layout store; mode 1: bias + flat.
struct GemmArgs {
  const __bf16* A[3]; const __bf16* W[3]; void* C[3]; float scale[3];
  const __bf16* bias; const int* flagp; int mode;
};

__global__ __launch_bounds__(256, 2)
void gemm_nt(GemmArgs ga)
{
  constexpr int K = 1024;
  __shared__ __align__(16) __bf16 As[128 * 32];
  __shared__ __align__(16) __bf16 Bs[64 * 32];

  const int z = blockIdx.z;
  const __bf16* __restrict__ A = ga.A[z];
  const __bf16* __restrict__ W = ga.W[z];
  void* __restrict__ C = ga.C[z];
  const float scale = ga.scale[z];
  const int mode = ga.mode;

  const int tid = threadIdx.x;
  const int lane = tid & 63;
  const int wave = tid >> 6;
  const int l15 = lane & 15;
  const int quad = lane >> 4;
  const int bm = blockIdx.y * 128;
  const int bn = blockIdx.x * 64;
  const int wm = (wave >> 1) * 64;
  const int wn = (wave & 1) * 32;

  const int srow = lane >> 2;
  const int scol = (lane & 3) * 8;

  f32x4 acc[4][2];
#pragma unroll
  for (int mi = 0; mi < 4; ++mi)
#pragma unroll
    for (int ni = 0; ni < 2; ++ni) {
      f32x4 zz = {0.f, 0.f, 0.f, 0.f};
      acc[mi][ni] = zz;
    }

  for (int kt = 0; kt < K / 32; ++kt) {
    const int k0 = kt * 32;
    __syncthreads();
#pragma unroll
    for (int c = 0; c < 2; ++c) {
      const int seg = wave + c * 4;
      async16(A + (size_t)(bm + seg * 16 + srow) * K + k0 + scol, As + seg * 512);
    }
    async16(W + (size_t)(bn + wave * 16 + srow) * K + k0 + scol, Bs + wave * 512);
    __syncthreads();

    bf16x8 af[4];
    bf16x8 bfr[2];
#pragma unroll
    for (int mi = 0; mi < 4; ++mi)
      af[mi] = *(const bf16x8*)(As + (wm + mi * 16 + l15) * 32 + quad * 8);
#pragma unroll
    for (int ni = 0; ni < 2; ++ni)
      bfr[ni] = *(const bf16x8*)(Bs + (wn + ni * 16 + l15) * 32 + quad * 8);
#pragma unroll
    for (int mi = 0; mi < 4; ++mi)
#pragma unroll
      for (int ni = 0; ni < 2; ++ni)
        acc[mi][ni] = MFMA16(af[mi], bfr[ni], acc[mi][ni]);
  }

  const int f = (mode == 1) ? *ga.flagp : 0;
#pragma unroll
  for (int ni = 0; ni < 2; ++ni) {
    const int n = bn + wn + ni * 16 + l15;
    const float bv = (mode == 1) ? (float)ga.bias[n] : 0.0f;
#pragma unroll
    for (int mi = 0; mi < 4; ++mi) {
#pragma unroll
      for (int r = 0; r < 4; ++r) {
        const int m = bm + wm + mi * 16 + quad * 4 + r;
        const float v = acc[mi][ni][r] * scale + bv;
        if (mode == 0) {
          const int b = m >> 11, s = m & 2047, h = n >> 6, dk = n & 63;
          ((__bf16*)C)[((size_t)(b * 16 + h) * 2048 + s) * 64 + dk] = (__bf16)v;
        } else if (f) {
          ((float*)C)[(size_t)m * 1024 + n] = v;
        } else {
          ((__bf16*)C)[(size_t)m * 1024 + n] = (__bf16)v;
        }
      }
    }
  }
}

// Flash attention, S^T formulation.  One block = 64 q rows of one (b,h).
// Q pre-scaled by 1/8.  Q/K/V layout [B*H][2048][64] bf16.
// S^T = K·Q^T (A=K, B=Q): C-layout col=l15=q-local, row=quad*4+r=k  -> per-lane
// scalar softmax stats, and P is k-contiguous per lane (b64 stores, no sync).
// O^T = V^T·P: A=V^T (transposed-V LDS), B=P (per-wave LDS strip).
__global__ __launch_bounds__(256, 4)
void attn(const __bf16* __restrict__ Q,
          const __bf16* __restrict__ Kg,
          const __bf16* __restrict__ Vg,
          __bf16* __restrict__ O)
{
  __shared__ __align__(16) __bf16 Qs[64 * 64];     // swizzled
  __shared__ __align__(16) __bf16 Ks[64 * 64];     // swizzled
  __shared__ __align__(16) __bf16 Vts[64][72];     // Vts[d][k]; reused as Ot[q][d]
  __shared__ __align__(16) __bf16 PsT[4][16][72];  // per-wave P[q-local][k]

  const int tid = threadIdx.x;
  const int lane = tid & 63;
  const int wave = tid >> 6;
  const int l15 = lane & 15;
  const int quad = lane >> 4;

  // balanced causal mapping: each CU's resident set sums to 66 tile-iters
  int zb = blockIdx.x, qt, bh;
  if (zb < 512) { qt = zb & 31; bh = zb >> 5; }
  else { int z2 = zb - 512; qt = 31 - (z2 & 31); bh = 16 + (z2 >> 5); }
  const int q0 = qt * 64;

  const __bf16* Qp = Q + (size_t)bh * 2048 * 64;
  const __bf16* Kp = Kg + (size_t)bh * 2048 * 64;
  const __bf16* Vp = Vg + (size_t)bh * 2048 * 64;

  // stage Q (swizzled, async): LDS chunk d = r*256 + wave*64 + lane
#pragma unroll
  for (int r = 0; r < 2; ++r) {
    const int d = r * 256 + wave * 64 + lane;
    const int row = d >> 3, c = (d & 7) ^ (row & 7);
    async16(Qp + (size_t)(q0 + row) * 64 + c * 8, (char*)Qs + (r * 256 + wave * 64) * 16);
  }

  f32x4 o_[4];
#pragma unroll
  for (int dt = 0; dt < 4; ++dt) {
    f32x4 zz = {0.f, 0.f, 0.f, 0.f};
    o_[dt] = zz;
  }
  float mrow = -1e30f, lrow = 0.0f;
  const int qrow = wave * 16 + l15;   // q local to the 64-tile

  for (int kt = 0; kt <= qt; ++kt) {
    const int k0 = kt * 64;
    __syncthreads();
    // stage K (swizzled, async)
#pragma unroll
    for (int r = 0; r < 2; ++r) {
      const int d = r * 256 + wave * 64 + lane;
      const int row = d >> 3, c = (d & 7) ^ (row & 7);
      async16(Kp + (size_t)(k0 + row) * 64 + c * 8, (char*)Ks + (r * 256 + wave * 64) * 16);
    }
    // stage V transposed: paired-k bf16x2 stores (conflict-free)
    {
      const int kp = tid & 31, dg = tid >> 5;
      bf16x8 v0 = *(const bf16x8*)(Vp + (size_t)(k0 + 2 * kp) * 64 + dg * 8);
      bf16x8 v1 = *(const bf16x8*)(Vp + (size_t)(k0 + 2 * kp + 1) * 64 + dg * 8);
#pragma unroll
      for (int j = 0; j < 8; ++j) {
        bf16x2 pr = { v0[j], v1[j] };
        *(bf16x2*)(&Vts[dg * 8 + j][2 * kp]) = pr;
      }
    }
    __syncthreads();

    // S^T tiles: rows = k (quad*4+r), cols = q-local (l15)
    f32x4 st[4];
#pragma unroll
    for (int nt = 0; nt < 4; ++nt) {
      f32x4 zz = {0.f, 0.f, 0.f, 0.f};
      st[nt] = zz;
    }
#pragma unroll
    for (int kc = 0; kc < 2; ++kc) {
      bf16x8 qf = lds_swz_read(Qs, qrow, kc * 4 + quad);
#pragma unroll
      for (int nt = 0; nt < 4; ++nt) {
        bf16x8 kf = lds_swz_read(Ks, nt * 16 + l15, kc * 4 + quad);
        st[nt] = MFMA16(kf, qf, st[nt]);
      }
    }

    if (kt == qt) {  // diagonal: mask k > q
#pragma unroll
      for (int nt = 0; nt < 4; ++nt)
#pragma unroll
        for (int r = 0; r < 4; ++r)
          if (nt * 16 + quad * 4 + r > qrow) st[nt][r] = -1e30f;
    }

    // online softmax: per-lane scalar stats (q = qrow), reduce over quads
    float tmax = -1e30f;
#pragma unroll
    for (int nt = 0; nt < 4; ++nt)
#pragma unroll
      for (int r = 0; r < 4; ++r) tmax = fmaxf(tmax, st[nt][r]);
    tmax = fmaxf(tmax, __shfl_xor(tmax, 16, 64));
    tmax = fmaxf(tmax, __shfl_xor(tmax, 32, 64));
    const float mnew = fmaxf(mrow, tmax);
    const float alpha = __expf(mrow - mnew);
    float rs = 0.0f;
    bf16x4 pd[4];
#pragma unroll
    for (int nt = 0; nt < 4; ++nt)
#pragma unroll
      for (int r = 0; r < 4; ++r) {
        const float pv = __expf(st[nt][r] - mnew);
        rs += pv;
        pd[nt][r] = (__bf16)pv;
      }
    rs += __shfl_xor(rs, 16, 64);
    rs += __shfl_xor(rs, 32, 64);
    lrow = lrow * alpha + rs;
    mrow = mnew;
#pragma unroll
    for (int dt = 0; dt < 4; ++dt) o_[dt] *= alpha;

    // P to per-wave LDS strip: b64 stores, same-wave consumer -> no barrier
#pragma unroll
    for (int nt = 0; nt < 4; ++nt)
      *(bf16x4*)(&PsT[wave][l15][nt * 16 + quad * 4]) = pd[nt];

    // O^T += V^T · P
#pragma unroll
    for (int kc = 0; kc < 2; ++kc) {
      bf16x8 pf = *(const bf16x8*)(&PsT[wave][l15][kc * 32 + quad * 8]);
#pragma unroll
      for (int dt = 0; dt < 4; ++dt) {
        bf16x8 vf = *(const bf16x8*)(&Vts[dt * 16 + l15][kc * 32 + quad * 8]);
        o_[dt] = MFMA16(vf, pf, o_[dt]);
      }
    }
  }

  // epilogue: normalize, transpose through LDS (reuse Vts as Ot[q][d]), store.
  // o_[dt][r] = O[q = wave*16 + l15][d = dt*16 + quad*4 + r]
  __syncthreads();
  const float inv_l = 1.0f / lrow;
#pragma unroll
  for (int dt = 0; dt < 4; ++dt)
#pragma unroll
    for (int r = 0; r < 4; r += 2) {
      bf16x2 pr = { (__bf16)(o_[dt][r] * inv_l), (__bf16)(o_[dt][r + 1] * inv_l) };
      // FIX(r3): row is the tile-global q = wave*16 + l15 (was l15 -> waves
      // clobbered rows 0..15 and rows 16..63 kept stale V^T data).
      *(bf16x2*)(&Vts[wave * 16 + l15][dt * 16 + quad * 4 + r]) = pr;
    }
  __syncthreads();

  const int b = bh >> 4, h = bh & 15;
#pragma unroll
  for (int t = 0; t < 2; ++t) {
    const int i = tid + t * 256;
    const int row = i >> 3, c = i & 7;
    f32x4 v = *(const f32x4*)(&Vts[row][c * 8]);
    *(f32x4*)(O + (size_t)(b * 2048 + q0 + row) * 1024 + h * 64 + c * 8) = v;
  }
}

extern "C" void kernel_launch(void* const* d_in, const int* in_sizes, int n_in,
                              void* d_out, int out_size, void* d_ws, size_t ws_size,
                              hipStream_t stream) {
  char* ws = (char*)d_ws;
  int* flag = (int*)ws;
  __bf16* Xc0 = (__bf16*)(ws + (1u << 20));    // 8 MB each
  __bf16* Xc1 = (__bf16*)(ws + (9u << 20));
  __bf16* Xc2 = (__bf16*)(ws + (17u << 20));
  __bf16* Wc0 = (__bf16*)(ws + (25u << 20));   // 2 MB each
  __bf16* Wc1 = (__bf16*)(ws + (27u << 20));
  __bf16* Wc2 = (__bf16*)(ws + (29u << 20));
  __bf16* Wc3 = (__bf16*)(ws + (31u << 20));
  __bf16* bc  = (__bf16*)(ws + (33u << 20));
  __bf16* Qw  = (__bf16*)(ws + (34u << 20));   // 8 MB each, [B*H][S][64]
  __bf16* Kw  = (__bf16*)(ws + (42u << 20));
  __bf16* Vw  = (__bf16*)(ws + (50u << 20));
  __bf16* Aw  = Xc0;                           // X dead after projections

  detect_dtype<<<1, 256, 0, stream>>>((const uint16_t*)d_in[4], flag);

  CvtArgs ca;
  ca.src[0] = d_in[0]; ca.dst[0] = Xc0; ca.n[0] = 4194304;
  ca.src[1] = d_in[1]; ca.dst[1] = Xc1; ca.n[1] = 4194304;
  ca.src[2] = d_in[2]; ca.dst[2] = Xc2; ca.n[2] = 4194304;
  ca.src[3] = d_in[4]; ca.dst[3] = Wc0; ca.n[3] = 1048576;
  ca.src[4] = d_in[5]; ca.dst[4] = Wc1; ca.n[4] = 1048576;
  ca.src[5] = d_in[6]; ca.dst[5] = Wc2; ca.n[5] = 1048576;
  ca.src[6] = d_in[7]; ca.dst[6] = Wc3; ca.n[6] = 1048576;
  ca.src[7] = d_in[8]; ca.dst[7] = bc;  ca.n[7] = 1024;
  convert_all<<<dim3(2048, 8), 256, 0, stream>>>(ca, flag);

  // fused Q/K/V projections (scores scale 1/8 folded into Q)
  GemmArgs g0;
  g0.A[0] = Xc0; g0.W[0] = Wc0; g0.C[0] = Qw; g0.scale[0] = 0.125f;
  g0.A[1] = Xc1; g0.W[1] = Wc1; g0.C[1] = Kw; g0.scale[1] = 1.0f;
  g0.A[2] = Xc2; g0.W[2] = Wc2; g0.C[2] = Vw; g0.scale[2] = 1.0f;
  g0.bias = nullptr; g0.flagp = flag; g0.mode = 0;
  gemm_nt<<<dim3(16, 32, 3), 256, 0, stream>>>(g0);

  attn<<<dim3(1024), 256, 0, stream>>>(Qw, Kw, Vw, Aw);

  GemmArgs g1;
  g1.A[0] = Aw; g1.W[0] = Wc3; g1.C[0] = d_out; g1.scale[0] = 1.0f;
  g1.A[1] = nullptr; g1.W[1] = nullptr; g1.C[1] = nullptr; g1.scale[1] = 0.f;
  g1.A[2] = nullptr; g1.W[2] = nullptr; g1.C[2] = nullptr; g1.scale[2] = 0.f;
  g1.bias = bc; g1.flagp = flag; g1.mode = 1;
  gemm_nt<<<dim3(16, 32, 1), 256, 0, stream>>>(g1);
}

// Round 5
// 252.741 us; speedup vs baseline: 1.5576x; 1.0270x over previous
//
#include <hip/hip_runtime.h>
#include <hip/hip_bf16.h>
#include <stdint.h>

// Problem: B=2, S=2048, D=1024, H=16, DK=64.  M = B*S = 4096.
// Dtype detected at runtime (fp32 vs bf16), canonicalized to bf16.

typedef __attribute__((ext_vector_type(4))) float  f32x4;
typedef __attribute__((ext_vector_type(4))) int    i32x4;
typedef __attribute__((ext_vector_type(8))) __bf16 bf16x8;
typedef __attribute__((ext_vector_type(4))) __bf16 bf16x4;
typedef __attribute__((ext_vector_type(2))) __bf16 bf16x2;

#define MFMA16(a, b, c) __builtin_amdgcn_mfma_f32_16x16x32_bf16((a), (b), (c), 0, 0, 0)

__device__ __forceinline__ void async16(const void* g, void* lds) {
  __builtin_amdgcn_global_load_lds(
      (const __attribute__((address_space(1))) uint32_t*)g,
      (__attribute__((address_space(3))) uint32_t*)lds,
      16, 0, 0);
}

// XOR-swizzled LDS tile (64x64 bf16): element (row, col/8) stored at chunk
// row*8 + ((col/8) ^ (row&7)).  Unpadded, ~2-way (free) on frag reads.
__device__ __forceinline__ bf16x8 lds_swz_read(const __bf16* base, int row, int cchunk) {
  const int sw = cchunk ^ (row & 7);
  return *(const bf16x8*)((const char*)base + row * 128 + sw * 16);
}

// ---- dtype detector: read w_q as bf16; fp32 mantissa low-halves decode huge.
__global__ void detect_dtype(const uint16_t* __restrict__ w, int* __restrict__ flag) {
  __shared__ int s;
  if (threadIdx.x == 0) s = 0;
  __syncthreads();
  int big = 0;
  for (int i = threadIdx.x; i < 8192; i += 256) {
    uint32_t u = ((uint32_t)w[i]) << 16;
    float f;
    __builtin_memcpy(&f, &u, 4);
    if (fabsf(f) > 1.0f) big = 1;   // xavier bound is 0.054
  }
  if (big) atomicOr(&s, 1);
  __syncthreads();
  if (threadIdx.x == 0) *flag = s;  // 1 = fp32 inputs, 0 = bf16 inputs
}

// ---- canonicalize all float tensors to bf16
struct CvtArgs { const void* src[8]; void* dst[8]; int n[8]; };

__global__ __launch_bounds__(256)
void convert_all(CvtArgs a, const int* __restrict__ flagp) {
  const int t = blockIdx.y;
  const int n = a.n[t];
  const int i0 = (blockIdx.x * 256 + threadIdx.x) * 8;
  if (i0 >= n) return;
  const int f = *flagp;
  if (f) {
    const float* s = (const float*)a.src[t];
    __bf16* d = (__bf16*)a.dst[t];
    bf16x8 v;
#pragma unroll
    for (int j = 0; j < 8; ++j) v[j] = (__bf16)s[i0 + j];
    *(bf16x8*)(d + i0) = v;
  } else {
    const i32x4* s = (const i32x4*)((const char*)a.src[t] + (size_t)i0 * 2);
    i32x4* d = (i32x4*)((char*)a.dst[t] + (size_t)i0 * 2);
    *d = *s;
  }
}

// C = A[4096,1024] @ W[1024,1024]^T  (NT, both K-contiguous, bf16).
// m97-style 128x128 tile, BK=32: 4 waves x (64x64), 16 MFMA/wave/K-step.
// z-batched over up to 3 tensors.  mode 0: QKV layout store; mode 1: bias + flat.
struct GemmArgs {
  const __bf16* A[3]; const __bf16* W[3]; void* C[3]; float scale[3];
  const __bf16* bias; const int* flagp; int mode;
};

__global__ __launch_bounds__(256, 2)
void gemm_nt(GemmArgs ga)
{
  constexpr int K = 1024;
  __shared__ __align__(16) __bf16 As[128 * 32];
  __shared__ __align__(16) __bf16 Bs[128 * 32];

  const int z = blockIdx.z;
  const __bf16* __restrict__ A = ga.A[z];
  const __bf16* __restrict__ W = ga.W[z];
  void* __restrict__ C = ga.C[z];
  const float scale = ga.scale[z];
  const int mode = ga.mode;

  const int tid = threadIdx.x;
  const int lane = tid & 63;
  const int wave = tid >> 6;
  const int l15 = lane & 15;
  const int quad = lane >> 4;
  const int bm = blockIdx.y * 128;
  const int bn = blockIdx.x * 128;
  const int wm = (wave >> 1) * 64;
  const int wn = (wave & 1) * 64;

  f32x4 acc[4][4];
#pragma unroll
  for (int mi = 0; mi < 4; ++mi)
#pragma unroll
    for (int ni = 0; ni < 4; ++ni) {
      f32x4 zz = {0.f, 0.f, 0.f, 0.f};
      acc[mi][ni] = zz;
    }

  for (int kt = 0; kt < K / 32; ++kt) {
    const int k0 = kt * 32;
    __syncthreads();
    // A tile 128x32 = 512 16B-chunks; chunk = r*256 + wave*64 + lane,
    // row = chunk>>2, c = chunk&3.  Same for B.
#pragma unroll
    for (int r = 0; r < 2; ++r) {
      const int chunk = r * 256 + wave * 64 + lane;
      const int row = chunk >> 2, c = chunk & 3;
      async16(A + (size_t)(bm + row) * K + k0 + c * 8, As + (r * 256 + wave * 64) * 8);
      async16(W + (size_t)(bn + row) * K + k0 + c * 8, Bs + (r * 256 + wave * 64) * 8);
    }
    __syncthreads();

    bf16x8 af[4];
    bf16x8 bfr[4];
#pragma unroll
    for (int mi = 0; mi < 4; ++mi)
      af[mi] = *(const bf16x8*)(As + (wm + mi * 16 + l15) * 32 + quad * 8);
#pragma unroll
    for (int ni = 0; ni < 4; ++ni)
      bfr[ni] = *(const bf16x8*)(Bs + (wn + ni * 16 + l15) * 32 + quad * 8);
#pragma unroll
    for (int mi = 0; mi < 4; ++mi)
#pragma unroll
      for (int ni = 0; ni < 4; ++ni)
        acc[mi][ni] = MFMA16(af[mi], bfr[ni], acc[mi][ni]);
  }

  const int f = (mode == 1) ? *ga.flagp : 0;
#pragma unroll
  for (int ni = 0; ni < 4; ++ni) {
    const int n = bn + wn + ni * 16 + l15;
    const float bv = (mode == 1) ? (float)ga.bias[n] : 0.0f;
#pragma unroll
    for (int mi = 0; mi < 4; ++mi) {
#pragma unroll
      for (int r = 0; r < 4; ++r) {
        const int m = bm + wm + mi * 16 + quad * 4 + r;
        const float v = acc[mi][ni][r] * scale + bv;
        if (mode == 0) {
          const int b = m >> 11, s = m & 2047, h = n >> 6, dk = n & 63;
          ((__bf16*)C)[((size_t)(b * 16 + h) * 2048 + s) * 64 + dk] = (__bf16)v;
        } else if (f) {
          ((float*)C)[(size_t)m * 1024 + n] = v;
        } else {
          ((__bf16*)C)[(size_t)m * 1024 + n] = (__bf16)v;
        }
      }
    }
  }
}

// Flash attention, S^T formulation.  One block = 64 q rows of one (b,h).
// Q pre-scaled by 1/8.  Q/K/V layout [B*H][2048][64] bf16.
// S^T = K·Q^T (A=K, B=Q): C-layout col=l15=q-local, row=quad*4+r=k  -> per-lane
// scalar softmax stats, and P is k-contiguous per lane (b64 stores, no sync).
// O^T = V^T·P: A=V^T (transposed-V LDS), B=P (per-wave LDS strip).
__global__ __launch_bounds__(256, 4)
void attn(const __bf16* __restrict__ Q,
          const __bf16* __restrict__ Kg,
          const __bf16* __restrict__ Vg,
          __bf16* __restrict__ O)
{
  __shared__ __align__(16) __bf16 Qs[64 * 64];     // swizzled
  __shared__ __align__(16) __bf16 Ks[64 * 64];     // swizzled
  __shared__ __align__(16) __bf16 Vts[64][72];     // Vts[d][k]; reused as Ot[q][d]
  __shared__ __align__(16) __bf16 PsT[4][16][72];  // per-wave P[q-local][k]

  const int tid = threadIdx.x;
  const int lane = tid & 63;
  const int wave = tid >> 6;
  const int l15 = lane & 15;
  const int quad = lane >> 4;

  // balanced causal mapping: each CU's resident set sums to 66 tile-iters
  int zb = blockIdx.x, qt, bh;
  if (zb < 512) { qt = zb & 31; bh = zb >> 5; }
  else { int z2 = zb - 512; qt = 31 - (z2 & 31); bh = 16 + (z2 >> 5); }
  const int q0 = qt * 64;

  const __bf16* Qp = Q + (size_t)bh * 2048 * 64;
  const __bf16* Kp = Kg + (size_t)bh * 2048 * 64;
  const __bf16* Vp = Vg + (size_t)bh * 2048 * 64;

  // stage Q (swizzled, async): LDS chunk d = r*256 + wave*64 + lane
#pragma unroll
  for (int r = 0; r < 2; ++r) {
    const int d = r * 256 + wave * 64 + lane;
    const int row = d >> 3, c = (d & 7) ^ (row & 7);
    async16(Qp + (size_t)(q0 + row) * 64 + c * 8, (char*)Qs + (r * 256 + wave * 64) * 16);
  }

  f32x4 o_[4];
#pragma unroll
  for (int dt = 0; dt < 4; ++dt) {
    f32x4 zz = {0.f, 0.f, 0.f, 0.f};
    o_[dt] = zz;
  }
  float mrow = -1e30f, lrow = 0.0f;
  const int qrow = wave * 16 + l15;   // q local to the 64-tile

  // Q fragments are K-loop invariant: hoist out of the loop (r4)
  __syncthreads();
  bf16x8 qf[2];
#pragma unroll
  for (int kc = 0; kc < 2; ++kc) qf[kc] = lds_swz_read(Qs, qrow, kc * 4 + quad);

  for (int kt = 0; kt <= qt; ++kt) {
    const int k0 = kt * 64;
    __syncthreads();
    // stage K (swizzled, async)
#pragma unroll
    for (int r = 0; r < 2; ++r) {
      const int d = r * 256 + wave * 64 + lane;
      const int row = d >> 3, c = (d & 7) ^ (row & 7);
      async16(Kp + (size_t)(k0 + row) * 64 + c * 8, (char*)Ks + (r * 256 + wave * 64) * 16);
    }
    // stage V transposed: paired-k bf16x2 stores (2-way, free)
    {
      const int kp = tid & 31, dg = tid >> 5;
      bf16x8 v0 = *(const bf16x8*)(Vp + (size_t)(k0 + 2 * kp) * 64 + dg * 8);
      bf16x8 v1 = *(const bf16x8*)(Vp + (size_t)(k0 + 2 * kp + 1) * 64 + dg * 8);
#pragma unroll
      for (int j = 0; j < 8; ++j) {
        bf16x2 pr = { v0[j], v1[j] };
        *(bf16x2*)(&Vts[dg * 8 + j][2 * kp]) = pr;
      }
    }
    __syncthreads();

    // S^T tiles: rows = k (quad*4+r), cols = q-local (l15)
    f32x4 st[4];
#pragma unroll
    for (int nt = 0; nt < 4; ++nt) {
      f32x4 zz = {0.f, 0.f, 0.f, 0.f};
      st[nt] = zz;
    }
#pragma unroll
    for (int kc = 0; kc < 2; ++kc) {
#pragma unroll
      for (int nt = 0; nt < 4; ++nt) {
        bf16x8 kf = lds_swz_read(Ks, nt * 16 + l15, kc * 4 + quad);
        st[nt] = MFMA16(kf, qf[kc], st[nt]);
      }
    }

    if (kt == qt) {  // diagonal: mask k > q
#pragma unroll
      for (int nt = 0; nt < 4; ++nt)
#pragma unroll
        for (int r = 0; r < 4; ++r)
          if (nt * 16 + quad * 4 + r > qrow) st[nt][r] = -1e30f;
    }

    // online softmax: per-lane scalar stats (q = qrow), reduce over quads
    float tmax = -1e30f;
#pragma unroll
    for (int nt = 0; nt < 4; ++nt)
#pragma unroll
      for (int r = 0; r < 4; ++r) tmax = fmaxf(tmax, st[nt][r]);
    tmax = fmaxf(tmax, __shfl_xor(tmax, 16, 64));
    tmax = fmaxf(tmax, __shfl_xor(tmax, 32, 64));
    const float mnew = fmaxf(mrow, tmax);
    const float alpha = __expf(mrow - mnew);
    float rs = 0.0f;
    bf16x4 pd[4];
#pragma unroll
    for (int nt = 0; nt < 4; ++nt)
#pragma unroll
      for (int r = 0; r < 4; ++r) {
        const float pv = __expf(st[nt][r] - mnew);
        rs += pv;
        pd[nt][r] = (__bf16)pv;
      }
    rs += __shfl_xor(rs, 16, 64);
    rs += __shfl_xor(rs, 32, 64);
    lrow = lrow * alpha + rs;
    mrow = mnew;
#pragma unroll
    for (int dt = 0; dt < 4; ++dt) o_[dt] *= alpha;

    // P to per-wave LDS strip: b64 stores, same-wave consumer -> no barrier
#pragma unroll
    for (int nt = 0; nt < 4; ++nt)
      *(bf16x4*)(&PsT[wave][l15][nt * 16 + quad * 4]) = pd[nt];

    // O^T += V^T · P
#pragma unroll
    for (int kc = 0; kc < 2; ++kc) {
      bf16x8 pf = *(const bf16x8*)(&PsT[wave][l15][kc * 32 + quad * 8]);
#pragma unroll
      for (int dt = 0; dt < 4; ++dt) {
        bf16x8 vf = *(const bf16x8*)(&Vts[dt * 16 + l15][kc * 32 + quad * 8]);
        o_[dt] = MFMA16(vf, pf, o_[dt]);
      }
    }
  }

  // epilogue: normalize, transpose through LDS (reuse Vts as Ot[q][d]), store.
  // o_[dt][r] = O[q = wave*16 + l15][d = dt*16 + quad*4 + r]
  __syncthreads();
  const float inv_l = 1.0f / lrow;
#pragma unroll
  for (int dt = 0; dt < 4; ++dt)
#pragma unroll
    for (int r = 0; r < 4; r += 2) {
      bf16x2 pr = { (__bf16)(o_[dt][r] * inv_l), (__bf16)(o_[dt][r + 1] * inv_l) };
      *(bf16x2*)(&Vts[wave * 16 + l15][dt * 16 + quad * 4 + r]) = pr;
    }
  __syncthreads();

  const int b = bh >> 4, h = bh & 15;
#pragma unroll
  for (int t = 0; t < 2; ++t) {
    const int i = tid + t * 256;
    const int row = i >> 3, c = i & 7;
    f32x4 v = *(const f32x4*)(&Vts[row][c * 8]);
    *(f32x4*)(O + (size_t)(b * 2048 + q0 + row) * 1024 + h * 64 + c * 8) = v;
  }
}

extern "C" void kernel_launch(void* const* d_in, const int* in_sizes, int n_in,
                              void* d_out, int out_size, void* d_ws, size_t ws_size,
                              hipStream_t stream) {
  char* ws = (char*)d_ws;
  int* flag = (int*)ws;
  __bf16* Xc0 = (__bf16*)(ws + (1u << 20));    // 8 MB each
  __bf16* Xc1 = (__bf16*)(ws + (9u << 20));
  __bf16* Xc2 = (__bf16*)(ws + (17u << 20));
  __bf16* Wc0 = (__bf16*)(ws + (25u << 20));   // 2 MB each
  __bf16* Wc1 = (__bf16*)(ws + (27u << 20));
  __bf16* Wc2 = (__bf16*)(ws + (29u << 20));
  __bf16* Wc3 = (__bf16*)(ws + (31u << 20));
  __bf16* bc  = (__bf16*)(ws + (33u << 20));
  __bf16* Qw  = (__bf16*)(ws + (34u << 20));   // 8 MB each, [B*H][S][64]
  __bf16* Kw  = (__bf16*)(ws + (42u << 20));
  __bf16* Vw  = (__bf16*)(ws + (50u << 20));
  __bf16* Aw  = Xc0;                           // X dead after projections

  detect_dtype<<<1, 256, 0, stream>>>((const uint16_t*)d_in[4], flag);

  CvtArgs ca;
  ca.src[0] = d_in[0]; ca.dst[0] = Xc0; ca.n[0] = 4194304;
  ca.src[1] = d_in[1]; ca.dst[1] = Xc1; ca.n[1] = 4194304;
  ca.src[2] = d_in[2]; ca.dst[2] = Xc2; ca.n[2] = 4194304;
  ca.src[3] = d_in[4]; ca.dst[3] = Wc0; ca.n[3] = 1048576;
  ca.src[4] = d_in[5]; ca.dst[4] = Wc1; ca.n[4] = 1048576;
  ca.src[5] = d_in[6]; ca.dst[5] = Wc2; ca.n[5] = 1048576;
  ca.src[6] = d_in[7]; ca.dst[6] = Wc3; ca.n[6] = 1048576;
  ca.src[7] = d_in[8]; ca.dst[7] = bc;  ca.n[7] = 1024;
  convert_all<<<dim3(2048, 8), 256, 0, stream>>>(ca, flag);

  // fused Q/K/V projections (scores scale 1/8 folded into Q)
  GemmArgs g0;
  g0.A[0] = Xc0; g0.W[0] = Wc0; g0.C[0] = Qw; g0.scale[0] = 0.125f;
  g0.A[1] = Xc1; g0.W[1] = Wc1; g0.C[1] = Kw; g0.scale[1] = 1.0f;
  g0.A[2] = Xc2; g0.W[2] = Wc2; g0.C[2] = Vw; g0.scale[2] = 1.0f;
  g0.bias = nullptr; g0.flagp = flag; g0.mode = 0;
  gemm_nt<<<dim3(8, 32, 3), 256, 0, stream>>>(g0);

  attn<<<dim3(1024), 256, 0, stream>>>(Qw, Kw, Vw, Aw);

  GemmArgs g1;
  g1.A[0] = Aw; g1.W[0] = Wc3; g1.C[0] = d_out; g1.scale[0] = 1.0f;
  g1.A[1] = nullptr; g1.W[1] = nullptr; g1.C[1] = nullptr; g1.scale[1] = 0.f;
  g1.A[2] = nullptr; g1.W[2] = nullptr; g1.C[2] = nullptr; g1.scale[2] = 0.f;
  g1.bias = bc; g1.flagp = flag; g1.mode = 1;
  gemm_nt<<<dim3(8, 32, 1), 256, 0, stream>>>(g1);
}